// Round 1
// 8200.941 us; speedup vs baseline: 1.4570x; 1.4570x over previous
//
#include <hip/hip_runtime.h>

#define BATCH 2048
#define TTOT 48
#define TOUT 47
#define SS 128
#define HH 256
#define VV 96
#define MB 8                  // batch rows per block
#define NBLK (BATCH / MB)     // 256 -> one block per CU
#define NTHR 512              // 8 waves
#define SROW 260              // fp32 LDS row stride (16B-aligned)

// ---- transposed-weight workspace layout (float offsets). Requires ws_size >= 4.1 MB.
#define OFF_T0I 0             // [64][768][4]  Wih0 cols 96..351, k-major packed
#define OFF_T0H 196608        // [64][768][4]  Whh0
#define OFF_T1I 393216        // [64][768][4]  Wih1
#define OFF_T1H 589824        // [64][768][4]  Whh1
#define OFF_TG  786432        // [96][768]     Wih0 cols 0..95 (one-hot gather), i-major
#define OFF_TC  860160        // [2][64][256][4] wcW halves
#define OFF_TS  991232        // [64][96][4]   wsW
#define WS_FLOATS 1015808

struct __align__(16) SMem {
    float htF[MB * SROW];     // attentional hidden ht (prev step)
    float c0F[MB * SROW];     // GRU0 state
    float c1F[MB * SROW];     // GRU1 state (= "out")
    float cxF[MB * SROW];     // attention context
    float gI[MB * 768];       // x-side partials (K-half 0)   / wc partials
    float gH[MB * 768];       // h-side partials (K-half 0)   / wc partials
    float gI2[MB * 768];      // x-side partials (K-half 1)
    float gH2[MB * 768];      // h-side partials (K-half 1)
    int   ymS[MB];
};

__device__ __forceinline__ float dot4(const float4 a, const float4 b) {
    return a.x * b.x + a.y * b.y + a.z * b.z + a.w * b.w;
}

// GRU GEMV: 512 threads = (kh = tid>>8 in {0,1} K-half) x (i0 = tid&255).
// Each thread computes rows {i0, i0+256, i0+512} over K-range [kh*128, kh*128+128).
// Weight loads fully coalesced from k-major transposed TI/TH; x/h read as
// wave-uniform LDS broadcasts amortized over 3 rows (12 FMA per LDS instr).
__device__ __forceinline__ void gru_gemv2(
    const float* __restrict__ TI, const float* __restrict__ TH,
    const float* __restrict__ bih, const float* __restrict__ bhh,
    const float* xS, const float* hS,
    float* gI, float* gH, float* gI2, float* gH2, const int tid)
{
    const int kh = tid >> 8;
    const int i0 = tid & 255;
    const float* __restrict__ bI = TI + (size_t)kh * 98304;   // 32*768*4 floats
    const float* __restrict__ bH = TH + (size_t)kh * 98304;
    float aI0[MB], aI1[MB], aI2[MB], aH0[MB], aH1[MB], aH2[MB];
    const float bi0 = kh ? 0.f : bih[i0];
    const float bi1 = kh ? 0.f : bih[i0 + 256];
    const float bi2 = kh ? 0.f : bih[i0 + 512];
    const float bh0 = kh ? 0.f : bhh[i0];
    const float bh1 = kh ? 0.f : bhh[i0 + 256];
    const float bh2 = kh ? 0.f : bhh[i0 + 512];
    #pragma unroll
    for (int m = 0; m < MB; ++m) {
        aI0[m] = bi0; aI1[m] = bi1; aI2[m] = bi2;
        aH0[m] = bh0; aH1[m] = bh1; aH2[m] = bh2;
    }
    const float* xk = xS + kh * 128;
    const float* hk = hS + kh * 128;
    #pragma unroll 2
    for (int kk = 0; kk < 32; ++kk) {
        const float4 wi0 = *(const float4*)(bI + ((size_t)kk * 768 + i0) * 4);
        const float4 wi1 = *(const float4*)(bI + ((size_t)kk * 768 + i0 + 256) * 4);
        const float4 wi2 = *(const float4*)(bI + ((size_t)kk * 768 + i0 + 512) * 4);
        const float4 wh0 = *(const float4*)(bH + ((size_t)kk * 768 + i0) * 4);
        const float4 wh1 = *(const float4*)(bH + ((size_t)kk * 768 + i0 + 256) * 4);
        const float4 wh2 = *(const float4*)(bH + ((size_t)kk * 768 + i0 + 512) * 4);
        #pragma unroll
        for (int m = 0; m < MB; ++m) {
            const float4 x4 = *(const float4*)(xk + m * SROW + kk * 4);
            const float4 h4 = *(const float4*)(hk + m * SROW + kk * 4);
            aI0[m] += dot4(wi0, x4); aI1[m] += dot4(wi1, x4); aI2[m] += dot4(wi2, x4);
            aH0[m] += dot4(wh0, h4); aH1[m] += dot4(wh1, h4); aH2[m] += dot4(wh2, h4);
        }
    }
    float* dI = kh ? gI2 : gI;
    float* dH = kh ? gH2 : gH;
    #pragma unroll
    for (int m = 0; m < MB; ++m) {
        dI[m * 768 + i0]       = aI0[m];
        dI[m * 768 + i0 + 256] = aI1[m];
        dI[m * 768 + i0 + 512] = aI2[m];
        dH[m * 768 + i0]       = aH0[m];
        dH[m * 768 + i0 + 256] = aH1[m];
        dH[m * 768 + i0 + 512] = aH2[m];
    }
}

__global__ __launch_bounds__(NTHR, 2) void decoder_kernel(
    const int* __restrict__ y,
    const float* __restrict__ enc,
    const float* __restrict__ eh,
    const float* __restrict__ bih0,
    const float* __restrict__ bhh0,
    const float* __restrict__ bih1,
    const float* __restrict__ bhh1,
    const float* __restrict__ wcb,
    const float* __restrict__ wsb,
    const float* __restrict__ ws,
    float* __restrict__ out)
{
    __shared__ SMem sm;
    const int tid = threadIdx.x;
    const int b0 = blockIdx.x * MB;

    const float* __restrict__ T0I = ws + OFF_T0I;
    const float* __restrict__ T0H = ws + OFF_T0H;
    const float* __restrict__ T1I = ws + OFF_T1I;
    const float* __restrict__ T1H = ws + OFF_T1H;
    const float* __restrict__ TG  = ws + OFF_TG;
    const float* __restrict__ TC  = ws + OFF_TC;
    const float* __restrict__ TS  = ws + OFF_TS;

    // init: ht=0, c0=eh[0], c1=eh[1]
    for (int idx = tid; idx < MB * SROW; idx += NTHR) sm.htF[idx] = 0.f;
    for (int idx = tid; idx < MB * HH; idx += NTHR) {
        const int m = idx >> 8, k = idx & 255;
        sm.c0F[m * SROW + k] = eh[(b0 + m) * HH + k];
        sm.c1F[m * SROW + k] = eh[(size_t)BATCH * HH + (b0 + m) * HH + k];
    }
    __syncthreads();

    for (int t = 0; t < TOUT; ++t) {
        if (tid < MB) sm.ymS[tid] = y[(b0 + tid) * TTOT + t];

        // ---- GRU0 GEMV: x = ht(prev), h = c0
        gru_gemv2(T0I, T0H, bih0, bhh0, sm.htF, sm.c0F,
                  sm.gI, sm.gH, sm.gI2, sm.gH2, tid);
        __syncthreads();                               // (1) partials + ymS ready
        // ---- GRU0 update (combine K-halves + coalesced one-hot gather add)
        for (int p = tid; p < MB * 256; p += NTHR) {
            const int m = p >> 8, c = p & 255;
            const float* tg = TG + (size_t)sm.ymS[m] * 768;
            const float giR = sm.gI[m * 768 + c]       + sm.gI2[m * 768 + c]       + tg[c];
            const float ghR = sm.gH[m * 768 + c]       + sm.gH2[m * 768 + c];
            const float giZ = sm.gI[m * 768 + 256 + c] + sm.gI2[m * 768 + 256 + c] + tg[256 + c];
            const float ghZ = sm.gH[m * 768 + 256 + c] + sm.gH2[m * 768 + 256 + c];
            const float giN = sm.gI[m * 768 + 512 + c] + sm.gI2[m * 768 + 512 + c] + tg[512 + c];
            const float ghN = sm.gH[m * 768 + 512 + c] + sm.gH2[m * 768 + 512 + c];
            const float r = 1.f / (1.f + __expf(-(giR + ghR)));
            const float z = 1.f / (1.f + __expf(-(giZ + ghZ)));
            const float n = tanhf(giN + r * ghN);
            sm.c0F[m * SROW + c] = (1.f - z) * n + z * sm.c0F[m * SROW + c];
        }
        __syncthreads();                               // (2) c0 ready

        // ---- GRU1 GEMV: x = c0(new), h = c1
        gru_gemv2(T1I, T1H, bih1, bhh1, sm.c0F, sm.c1F,
                  sm.gI, sm.gH, sm.gI2, sm.gH2, tid);
        __syncthreads();                               // (3)
        // ---- GRU1 update
        for (int p = tid; p < MB * 256; p += NTHR) {
            const int m = p >> 8, c = p & 255;
            const float giR = sm.gI[m * 768 + c]       + sm.gI2[m * 768 + c];
            const float ghR = sm.gH[m * 768 + c]       + sm.gH2[m * 768 + c];
            const float giZ = sm.gI[m * 768 + 256 + c] + sm.gI2[m * 768 + 256 + c];
            const float ghZ = sm.gH[m * 768 + 256 + c] + sm.gH2[m * 768 + 256 + c];
            const float giN = sm.gI[m * 768 + 512 + c] + sm.gI2[m * 768 + 512 + c];
            const float ghN = sm.gH[m * 768 + 512 + c] + sm.gH2[m * 768 + 512 + c];
            const float r = 1.f / (1.f + __expf(-(giR + ghR)));
            const float z = 1.f / (1.f + __expf(-(giZ + ghZ)));
            const float n = tanhf(giN + r * ghN);
            sm.c1F[m * SROW + c] = (1.f - z) * n + z * sm.c1F[m * SROW + c];
        }
        __syncthreads();                               // (4) c1 (= out) ready

        // ---- fused attention: online softmax, single coalesced pass over enc.
        // One wave per batch row m; lane owns ctx[lane*4..lane*4+3].
        {
            const int m = tid >> 6, lane = tid & 63;
            const float4 o4 = *(const float4*)(sm.c1F + m * SROW + lane * 4);
            const float* er = enc + (size_t)(b0 + m) * SS * HH + lane * 4;
            float4 C = {0.f, 0.f, 0.f, 0.f};
            float D = 0.f, Mx = -3.0e38f;
            for (int s = 0; s < SS; s += 2) {
                const float4 a4 = *(const float4*)(er);
                const float4 b4 = *(const float4*)(er + HH);
                er += 2 * HH;
                float e0 = dot4(a4, o4);
                float e1 = dot4(b4, o4);
                #pragma unroll
                for (int off = 1; off < 64; off <<= 1) {
                    e0 += __shfl_xor(e0, off);
                    e1 += __shfl_xor(e1, off);
                }
                const float nm = fmaxf(Mx, fmaxf(e0, e1));
                const float sc = __expf(Mx - nm);
                const float p0 = __expf(e0 - nm);
                const float p1 = __expf(e1 - nm);
                D = D * sc + p0 + p1;
                C.x = C.x * sc + p0 * a4.x + p1 * b4.x;
                C.y = C.y * sc + p0 * a4.y + p1 * b4.y;
                C.z = C.z * sc + p0 * a4.z + p1 * b4.z;
                C.w = C.w * sc + p0 * a4.w + p1 * b4.w;
                Mx = nm;
            }
            const float inv = 1.f / D;
            float4 cx;
            cx.x = C.x * inv; cx.y = C.y * inv; cx.z = C.z * inv; cx.w = C.w * inv;
            *(float4*)(sm.cxF + m * SROW + lane * 4) = cx;
        }
        __syncthreads();                               // (5) ctx ready

        // ---- wc phase A: thread = (i0w = tid&127, sel = bit7, khf = bit8)
        // rows {i0w, i0w+128}, state = sel ? ctx : out, K-half = khf. Coalesced TC loads.
        {
            const int i0w = tid & 127;
            const int sel = (tid >> 7) & 1;
            const int khf = tid >> 8;
            const float* st = (sel ? sm.cxF : sm.c1F) + khf * 128;
            const float* base = TC + ((size_t)sel * 64 * 256 + (size_t)khf * 32 * 256) * 4;
            float a0[MB], a1[MB];
            #pragma unroll
            for (int m = 0; m < MB; ++m) { a0[m] = 0.f; a1[m] = 0.f; }
            #pragma unroll 2
            for (int kk = 0; kk < 32; ++kk) {
                const float4 w0 = *(const float4*)(base + ((size_t)kk * 256 + i0w) * 4);
                const float4 w1 = *(const float4*)(base + ((size_t)kk * 256 + i0w + 128) * 4);
                #pragma unroll
                for (int m = 0; m < MB; ++m) {
                    const float4 s4 = *(const float4*)(st + m * SROW + kk * 4);
                    a0[m] += dot4(w0, s4);
                    a1[m] += dot4(w1, s4);
                }
            }
            float* dst = sel ? sm.gH : sm.gI;
            #pragma unroll
            for (int m = 0; m < MB; ++m) {
                dst[m * 768 + khf * 256 + i0w]       = a0[m];
                dst[m * 768 + khf * 256 + i0w + 128] = a1[m];
            }
        }
        __syncthreads();                               // (6)
        // ---- wc phase B: ht = tanh(sum of 4 partials + b)
        for (int p = tid; p < MB * 256; p += NTHR) {
            const int m = p >> 8, i = p & 255;
            sm.htF[m * SROW + i] = tanhf(sm.gI[m * 768 + i] + sm.gI[m * 768 + 256 + i]
                                       + sm.gH[m * 768 + i] + sm.gH[m * 768 + 256 + i]
                                       + wcb[i]);
        }
        __syncthreads();                               // (7) ht ready

        // ---- ws: logits from transposed TS (coalesced)
        for (int p = tid; p < MB * VV; p += NTHR) {
            const int m = p / VV, v = p - m * VV;
            const float* h = sm.htF + m * SROW;
            float acc = wsb[v];
            #pragma unroll 4
            for (int k4 = 0; k4 < 64; ++k4)
                acc += dot4(*(const float4*)(TS + ((size_t)k4 * 96 + v) * 4),
                            *(const float4*)(h + k4 * 4));
            out[(size_t)((b0 + m) * TOUT + t) * VV + v] = acc;
        }
        // no barrier needed: next-step GEMV0 only reads htF (read/read with ws)
        // and writes gI/gH, which were fully consumed before barrier (7).
    }
}

// ---- weight pre-transpose into workspace (k-major, 4-k packed) ----
__global__ __launch_bounds__(256) void prep_kernel(
    const float* __restrict__ Wih0, const float* __restrict__ Whh0,
    const float* __restrict__ Wih1, const float* __restrict__ Whh1,
    const float* __restrict__ wcW,  const float* __restrict__ wsW,
    float* __restrict__ ws)
{
    const int idx = blockIdx.x * 256 + threadIdx.x;
    if (idx < OFF_T0H) {                                  // T0I: Wih0 h-part
        const int j = idx & 3, q = idx >> 2;
        const int i = q % 768, k4 = q / 768;
        ws[idx] = Wih0[i * 352 + 96 + k4 * 4 + j];
    } else if (idx < OFF_T1I) {                           // T0H
        const int v = idx - OFF_T0H;
        const int j = v & 3, q = v >> 2;
        const int i = q % 768, k4 = q / 768;
        ws[idx] = Whh0[i * 256 + k4 * 4 + j];
    } else if (idx < OFF_T1H) {                           // T1I
        const int v = idx - OFF_T1I;
        const int j = v & 3, q = v >> 2;
        const int i = q % 768, k4 = q / 768;
        ws[idx] = Wih1[i * 256 + k4 * 4 + j];
    } else if (idx < OFF_TG) {                            // T1H
        const int v = idx - OFF_T1H;
        const int j = v & 3, q = v >> 2;
        const int i = q % 768, k4 = q / 768;
        ws[idx] = Whh1[i * 256 + k4 * 4 + j];
    } else if (idx < OFF_TC) {                            // TG: one-hot columns
        const int v = idx - OFF_TG;
        const int col = v / 768, i = v % 768;
        ws[idx] = Wih0[i * 352 + col];
    } else if (idx < OFF_TS) {                            // TC
        const int v = idx - OFF_TC;
        const int j = v & 3, q = v >> 2;
        const int i = q & 255, q2 = q >> 8;
        const int k4 = q2 & 63, sel = q2 >> 6;
        ws[idx] = wcW[i * 512 + sel * 256 + k4 * 4 + j];
    } else if (idx < WS_FLOATS) {                         // TS
        const int v = idx - OFF_TS;
        const int j = v & 3, q = v >> 2;
        const int vv = q % 96, k4 = q / 96;
        ws[idx] = wsW[vv * 256 + k4 * 4 + j];
    }
}

extern "C" void kernel_launch(void* const* d_in, const int* in_sizes, int n_in,
                              void* d_out, int out_size, void* d_ws, size_t ws_size,
                              hipStream_t stream) {
    (void)in_sizes; (void)n_in; (void)out_size; (void)ws_size;
    const int* y = (const int*)d_in[0];
    const float* enc  = (const float*)d_in[1];
    const float* eh   = (const float*)d_in[2];
    // d_in[3] = is_training (always 1, teacher forcing)
    const float* Wih0 = (const float*)d_in[4];
    const float* Whh0 = (const float*)d_in[5];
    const float* bih0 = (const float*)d_in[6];
    const float* bhh0 = (const float*)d_in[7];
    const float* Wih1 = (const float*)d_in[8];
    const float* Whh1 = (const float*)d_in[9];
    const float* bih1 = (const float*)d_in[10];
    const float* bhh1 = (const float*)d_in[11];
    const float* wcW  = (const float*)d_in[12];
    const float* wcb  = (const float*)d_in[13];
    const float* wsW  = (const float*)d_in[14];
    const float* wsb  = (const float*)d_in[15];
    float* outp = (float*)d_out;
    float* wsp  = (float*)d_ws;   // needs >= WS_FLOATS * 4 = 4.1 MB

    prep_kernel<<<dim3(WS_FLOATS / 256), dim3(256), 0, stream>>>(
        Wih0, Whh0, Wih1, Whh1, wcW, wsW, wsp);
    decoder_kernel<<<dim3(NBLK), dim3(NTHR), 0, stream>>>(
        y, enc, eh, bih0, bhh0, bih1, bhh1, wcb, wsb, wsp, outp);
}

// Round 2
// 6803.965 us; speedup vs baseline: 1.7562x; 1.2053x over previous
//
#include <hip/hip_runtime.h>

#define BATCH 2048
#define TTOT 48
#define TOUT 47
#define SS 128
#define HH 256
#define VV 96
#define MB 8                  // batch rows per block
#define NBLK (BATCH / MB)     // 256 -> one block per CU (weights read once per CU per step)
#define NTHR 1024             // 16 waves -> 4 waves/SIMD

// ---- transposed-weight workspace layout (float offsets). Requires ws_size >= 4.1 MB.
#define OFF_T0I 0             // [64][768][4]  Wih0 cols 96..351, k-major packed
#define OFF_T0H 196608        // [64][768][4]  Whh0
#define OFF_T1I 393216        // [64][768][4]  Wih1
#define OFF_T1H 589824        // [64][768][4]  Whh1
#define OFF_TG  786432        // [96][768]     Wih0 cols 0..95 (one-hot gather), i-major
#define OFF_TC  860160        // [2][64][256][4] wcW halves
#define OFF_TS  991232        // [64][96][4]   wsW
#define WS_FLOATS 1015808

// Gate partial buffer: 12 chunks of [MB][256]:
// chunk = (kh*2+side)*3 + gate,  kh in {0,1} K-half, side 0=I 1=H, gate 0=r 1=z 2=n
// Aliased (time-multiplexed) by attention partials (first 4096 fl) and wc partials (first 8192 fl).
struct __align__(16) SMem {
    float ht[MB * 256];       // attentional hidden (prev step)
    float c0[MB * 256];       // GRU0 state
    float c1[MB * 256];       // GRU1 state (= "out")
    float cx[MB * 256];       // attention context
    float g[12 * 2048];       // 96 KB partials
    float Dp[2][MB];          // attention partial denominators
    float Mp[2][MB];          // attention partial maxima
    int   ym[MB];
};

__device__ __forceinline__ float dot4(const float4 a, const float4 b) {
    return a.x * b.x + a.y * b.y + a.z * b.z + a.w * b.w;
}

// Full wave64 sum via DPP (VALU pipe only, no LDS traffic).
// Canonical GCN sequence: row_shr 1,2,4,8 then bcast15 (rows 1,3), bcast31 (rows 2,3);
// lane 63 holds the total.
__device__ __forceinline__ float wave_sum64(float v) {
    v += __int_as_float(__builtin_amdgcn_update_dpp(0, __float_as_int(v), 0x111, 0xf, 0xf, true));
    v += __int_as_float(__builtin_amdgcn_update_dpp(0, __float_as_int(v), 0x112, 0xf, 0xf, true));
    v += __int_as_float(__builtin_amdgcn_update_dpp(0, __float_as_int(v), 0x114, 0xf, 0xf, true));
    v += __int_as_float(__builtin_amdgcn_update_dpp(0, __float_as_int(v), 0x118, 0xf, 0xf, true));
    v += __int_as_float(__builtin_amdgcn_update_dpp(0, __float_as_int(v), 0x142, 0xa, 0xf, true));
    v += __int_as_float(__builtin_amdgcn_update_dpp(0, __float_as_int(v), 0x143, 0xc, 0xf, true));
    return __int_as_float(__builtin_amdgcn_readlane(__float_as_int(v), 63));
}

// GRU GEMV phase, 1024 threads = (kh = tid>>9) x (side = (tid>>8)&1) x (i0 = tid&255).
// Thread computes gate rows {i0, i0+256, i0+512} of its side (I: x-input, H: h-input)
// over K-half kh. Weights coalesced from k-major transposed chunks; state reads are
// wave-uniform LDS broadcasts amortized over 3 rows x 8 m (24 FMA4 per b128 read).
__device__ __forceinline__ void gru_gemv(
    const float* __restrict__ TI, const float* __restrict__ TH,
    const float* __restrict__ bih, const float* __restrict__ bhh,
    const float* xS, const float* hS, float* g, const int tid)
{
    const int kh = tid >> 9;
    const int side = (tid >> 8) & 1;
    const int i0 = tid & 255;
    const float* __restrict__ bW = (side ? TH : TI) + (size_t)kh * 98304;  // 32*768*4
    const float* __restrict__ bias = side ? bhh : bih;
    const float* sk = (side ? hS : xS) + kh * 128;
    float a0[MB], a1[MB], a2[MB];
    const float b0v = kh ? 0.f : bias[i0];
    const float b1v = kh ? 0.f : bias[i0 + 256];
    const float b2v = kh ? 0.f : bias[i0 + 512];
    #pragma unroll
    for (int m = 0; m < MB; ++m) { a0[m] = b0v; a1[m] = b1v; a2[m] = b2v; }
    #pragma unroll 2
    for (int kk = 0; kk < 32; ++kk) {
        const float4 w0 = *(const float4*)(bW + ((size_t)kk * 768 + i0) * 4);
        const float4 w1 = *(const float4*)(bW + ((size_t)kk * 768 + i0 + 256) * 4);
        const float4 w2 = *(const float4*)(bW + ((size_t)kk * 768 + i0 + 512) * 4);
        #pragma unroll
        for (int m = 0; m < MB; ++m) {
            const float4 s4 = *(const float4*)(sk + m * 256 + kk * 4);
            a0[m] += dot4(w0, s4);
            a1[m] += dot4(w1, s4);
            a2[m] += dot4(w2, s4);
        }
    }
    const int cb = (kh * 2 + side) * 3 * 2048;
    #pragma unroll
    for (int m = 0; m < MB; ++m) {
        g[cb + m * 256 + i0]            = a0[m];
        g[cb + 2048 + m * 256 + i0]     = a1[m];
        g[cb + 4096 + m * 256 + i0]     = a2[m];
    }
}

// Combine 12 partial chunks -> GRU state update.
template <bool GATHER>
__device__ __forceinline__ void gru_update(
    const float* g, float* st, const float* __restrict__ TG, const int* ym, const int tid)
{
    for (int p = tid; p < MB * 256; p += NTHR) {
        const int m = p >> 8, c = p & 255;
        const float* gm = g + m * 256 + c;
        float iR = gm[0 * 2048] + gm[6 * 2048];
        float hR = gm[3 * 2048] + gm[9 * 2048];
        float iZ = gm[1 * 2048] + gm[7 * 2048];
        float hZ = gm[4 * 2048] + gm[10 * 2048];
        float iN = gm[2 * 2048] + gm[8 * 2048];
        const float hN = gm[5 * 2048] + gm[11 * 2048];
        if (GATHER) {
            const float* tg = TG + (size_t)ym[m] * 768;
            iR += tg[c]; iZ += tg[256 + c]; iN += tg[512 + c];
        }
        const float r = 1.f / (1.f + __expf(-(iR + hR)));
        const float z = 1.f / (1.f + __expf(-(iZ + hZ)));
        const float n = tanhf(iN + r * hN);
        st[p] = (1.f - z) * n + z * st[p];
    }
}

__global__ __launch_bounds__(NTHR, 4) void decoder_kernel(
    const int* __restrict__ y,
    const float* __restrict__ enc,
    const float* __restrict__ eh,
    const float* __restrict__ bih0,
    const float* __restrict__ bhh0,
    const float* __restrict__ bih1,
    const float* __restrict__ bhh1,
    const float* __restrict__ wcb,
    const float* __restrict__ wsb,
    const float* __restrict__ ws,
    float* __restrict__ out)
{
    __shared__ SMem sm;
    const int tid = threadIdx.x;
    const int b0 = blockIdx.x * MB;

    const float* __restrict__ T0I = ws + OFF_T0I;
    const float* __restrict__ T0H = ws + OFF_T0H;
    const float* __restrict__ T1I = ws + OFF_T1I;
    const float* __restrict__ T1H = ws + OFF_T1H;
    const float* __restrict__ TG  = ws + OFF_TG;
    const float* __restrict__ TC  = ws + OFF_TC;
    const float* __restrict__ TS  = ws + OFF_TS;

    // init: ht=0, c0=eh[0], c1=eh[1]
    for (int idx = tid; idx < MB * 256; idx += NTHR) {
        sm.ht[idx] = 0.f;
        sm.c0[idx] = eh[b0 * HH + idx];
        sm.c1[idx] = eh[(size_t)BATCH * HH + b0 * HH + idx];
    }
    __syncthreads();

    for (int t = 0; t < TOUT; ++t) {
        if (tid < MB) sm.ym[tid] = y[(b0 + tid) * TTOT + t];

        // ---- GRU0: x = ht(prev), h = c0
        gru_gemv(T0I, T0H, bih0, bhh0, sm.ht, sm.c0, sm.g, tid);
        __syncthreads();                               // (1) partials + ym ready
        gru_update<true>(sm.g, sm.c0, TG, sm.ym, tid);
        __syncthreads();                               // (2) c0 ready

        // ---- GRU1: x = c0(new), h = c1
        gru_gemv(T1I, T1H, bih1, bhh1, sm.c0, sm.c1, sm.g, tid);
        __syncthreads();                               // (3)
        gru_update<false>(sm.g, sm.c1, TG, sm.ym, tid);
        __syncthreads();                               // (4) c1 (= out) ready

        // ---- fused attention, 2 waves per batch row (s-halves), online softmax,
        //      DPP wave-reduce (no LDS ops), single coalesced pass over enc.
        {
            const int m = tid >> 7, sh = (tid >> 6) & 1, lane = tid & 63;
            const float4 o4 = *(const float4*)(sm.c1 + m * 256 + lane * 4);
            const float* er = enc + ((size_t)(b0 + m) * SS + sh * 64) * HH + lane * 4;
            float4 C = {0.f, 0.f, 0.f, 0.f};
            float D = 0.f, Mx = -3.0e38f;
            for (int s = 0; s < 64; s += 2) {
                const float4 a4 = *(const float4*)(er);
                const float4 b4 = *(const float4*)(er + HH);
                er += 2 * HH;
                const float e0 = wave_sum64(dot4(a4, o4));
                const float e1 = wave_sum64(dot4(b4, o4));
                const float nm = fmaxf(Mx, fmaxf(e0, e1));
                const float sc = __expf(Mx - nm);
                const float p0 = __expf(e0 - nm);
                const float p1 = __expf(e1 - nm);
                D = D * sc + p0 + p1;
                C.x = C.x * sc + p0 * a4.x + p1 * b4.x;
                C.y = C.y * sc + p0 * a4.y + p1 * b4.y;
                C.z = C.z * sc + p0 * a4.z + p1 * b4.z;
                C.w = C.w * sc + p0 * a4.w + p1 * b4.w;
                Mx = nm;
            }
            *(float4*)(sm.g + (sh * 8 + m) * 256 + lane * 4) = C;   // alias gate buf
            if (lane == 0) { sm.Dp[sh][m] = D; sm.Mp[sh][m] = Mx; }
        }
        __syncthreads();                               // (5) partial C/D/M ready
        // ---- merge the two s-half softmax states -> ctx
        for (int p = tid; p < MB * 256; p += NTHR) {
            const int m = p >> 8, h = p & 255;
            const float M0 = sm.Mp[0][m], M1 = sm.Mp[1][m];
            const float Mt = fmaxf(M0, M1);
            const float e0 = __expf(M0 - Mt), e1 = __expf(M1 - Mt);
            const float den = sm.Dp[0][m] * e0 + sm.Dp[1][m] * e1;
            const float num = sm.g[m * 256 + h] * e0 + sm.g[(8 + m) * 256 + h] * e1;
            sm.cx[p] = num / den;
        }
        __syncthreads();                               // (6) ctx ready

        // ---- wc phase A: thread = (i0w = tid&127, sel = bit7, khf = bit8, mh = bit9)
        {
            const int i0w = tid & 127;
            const int sel = (tid >> 7) & 1;
            const int khf = (tid >> 8) & 1;
            const int mh  = tid >> 9;
            const float* st = (sel ? sm.cx : sm.c1) + khf * 128;
            const float* base = TC + ((size_t)sel * 16384 + (size_t)khf * 8192) * 4;
            float a0[4], a1[4];
            #pragma unroll
            for (int q = 0; q < 4; ++q) { a0[q] = 0.f; a1[q] = 0.f; }
            #pragma unroll 2
            for (int kk = 0; kk < 32; ++kk) {
                const float4 w0 = *(const float4*)(base + ((size_t)kk * 256 + i0w) * 4);
                const float4 w1 = *(const float4*)(base + ((size_t)kk * 256 + i0w + 128) * 4);
                #pragma unroll
                for (int q = 0; q < 4; ++q) {
                    const float4 s4 = *(const float4*)(st + (mh * 4 + q) * 256 + kk * 4);
                    a0[q] += dot4(w0, s4);
                    a1[q] += dot4(w1, s4);
                }
            }
            #pragma unroll
            for (int q = 0; q < 4; ++q) {
                const int m = mh * 4 + q;
                sm.g[((sel * 2 + khf) * 8 + m) * 256 + i0w]       = a0[q];
                sm.g[((sel * 2 + khf) * 8 + m) * 256 + i0w + 128] = a1[q];
            }
        }
        __syncthreads();                               // (7) wc partials ready
        // ---- wc phase B: ht = tanh(sum of 4 partials + b)
        for (int p = tid; p < MB * 256; p += NTHR) {
            const int m = p >> 8, i = p & 255;
            sm.ht[p] = tanhf(sm.g[(0 * 8 + m) * 256 + i] + sm.g[(1 * 8 + m) * 256 + i]
                           + sm.g[(2 * 8 + m) * 256 + i] + sm.g[(3 * 8 + m) * 256 + i]
                           + wcb[i]);
        }
        __syncthreads();                               // (8) ht ready

        // ---- ws: logits from transposed TS (coalesced)
        for (int p = tid; p < MB * VV; p += NTHR) {
            const int m = p / VV, v = p - m * VV;
            const float* h = sm.ht + m * 256;
            float acc = wsb[v];
            #pragma unroll 4
            for (int k4 = 0; k4 < 64; ++k4)
                acc += dot4(*(const float4*)(TS + ((size_t)k4 * 96 + v) * 4),
                            *(const float4*)(h + k4 * 4));
            out[(size_t)((b0 + m) * TOUT + t) * VV + v] = acc;
        }
        // no end-of-step barrier needed: ws reads only ht (b8-protected); next GEMV0
        // writes g (last read in wcB, before b8) and reads ht/c0 (stable).
    }
}

// ---- weight pre-transpose into workspace (k-major, 4-k packed) ----
__global__ __launch_bounds__(256) void prep_kernel(
    const float* __restrict__ Wih0, const float* __restrict__ Whh0,
    const float* __restrict__ Wih1, const float* __restrict__ Whh1,
    const float* __restrict__ wcW,  const float* __restrict__ wsW,
    float* __restrict__ ws)
{
    const int idx = blockIdx.x * 256 + threadIdx.x;
    if (idx < OFF_T0H) {                                  // T0I: Wih0 h-part
        const int j = idx & 3, q = idx >> 2;
        const int i = q % 768, k4 = q / 768;
        ws[idx] = Wih0[i * 352 + 96 + k4 * 4 + j];
    } else if (idx < OFF_T1I) {                           // T0H
        const int v = idx - OFF_T0H;
        const int j = v & 3, q = v >> 2;
        const int i = q % 768, k4 = q / 768;
        ws[idx] = Whh0[i * 256 + k4 * 4 + j];
    } else if (idx < OFF_T1H) {                           // T1I
        const int v = idx - OFF_T1I;
        const int j = v & 3, q = v >> 2;
        const int i = q % 768, k4 = q / 768;
        ws[idx] = Wih1[i * 256 + k4 * 4 + j];
    } else if (idx < OFF_TG) {                            // T1H
        const int v = idx - OFF_T1H;
        const int j = v & 3, q = v >> 2;
        const int i = q % 768, k4 = q / 768;
        ws[idx] = Whh1[i * 256 + k4 * 4 + j];
    } else if (idx < OFF_TC) {                            // TG: one-hot columns
        const int v = idx - OFF_TG;
        const int col = v / 768, i = v % 768;
        ws[idx] = Wih0[i * 352 + col];
    } else if (idx < OFF_TS) {                            // TC
        const int v = idx - OFF_TC;
        const int j = v & 3, q = v >> 2;
        const int i = q & 255, q2 = q >> 8;
        const int k4 = q2 & 63, sel = q2 >> 6;
        ws[idx] = wcW[i * 512 + sel * 256 + k4 * 4 + j];
    } else if (idx < WS_FLOATS) {                         // TS
        const int v = idx - OFF_TS;
        const int j = v & 3, q = v >> 2;
        const int vv = q % 96, k4 = q / 96;
        ws[idx] = wsW[vv * 256 + k4 * 4 + j];
    }
}

extern "C" void kernel_launch(void* const* d_in, const int* in_sizes, int n_in,
                              void* d_out, int out_size, void* d_ws, size_t ws_size,
                              hipStream_t stream) {
    (void)in_sizes; (void)n_in; (void)out_size; (void)ws_size;
    const int* y = (const int*)d_in[0];
    const float* enc  = (const float*)d_in[1];
    const float* eh   = (const float*)d_in[2];
    // d_in[3] = is_training (always 1, teacher forcing)
    const float* Wih0 = (const float*)d_in[4];
    const float* Whh0 = (const float*)d_in[5];
    const float* bih0 = (const float*)d_in[6];
    const float* bhh0 = (const float*)d_in[7];
    const float* Wih1 = (const float*)d_in[8];
    const float* Whh1 = (const float*)d_in[9];
    const float* bih1 = (const float*)d_in[10];
    const float* bhh1 = (const float*)d_in[11];
    const float* wcW  = (const float*)d_in[12];
    const float* wcb  = (const float*)d_in[13];
    const float* wsW  = (const float*)d_in[14];
    const float* wsb  = (const float*)d_in[15];
    float* outp = (float*)d_out;
    float* wsp  = (float*)d_ws;   // needs >= WS_FLOATS * 4 = 4.1 MB

    prep_kernel<<<dim3(WS_FLOATS / 256), dim3(256), 0, stream>>>(
        Wih0, Whh0, Wih1, Whh1, wcW, wsW, wsp);
    decoder_kernel<<<dim3(NBLK), dim3(NTHR), 0, stream>>>(
        y, enc, eh, bih0, bhh0, bih1, bhh1, wcb, wsb, wsp, outp);
}